// Round 9
// baseline (78.809 us; speedup 1.0000x reference)
//
#include <hip/hip_runtime.h>
#include <cstdio>

#define NNODE 5000
#define KK1 17
#define NT 80000                  // 16 slices * 5000
#define NREST 70000               // 14 slices * 5000 for d_w

typedef unsigned short u16;
typedef unsigned int u32;

__device__ __forceinline__ u16 f2bf(float x) {
  u32 u = __float_as_uint(x);
  return (u16)((u + 0x7fffu + ((u >> 16) & 1u)) >> 16);  // RNE
}
__device__ __forceinline__ float bfLo(u32 w){ return __uint_as_float(w << 16); }
__device__ __forceinline__ float bfHi(u32 w){ return __uint_as_float(w & 0xffff0000u); }

// ---------------------------------------------------------------------------
// k_prep: feat -> gS [bt*4+h][n][16] bf16, a8/b8 [m][32] bf16 (m = bt*5000+n),
// plus nnT[k][n] transpose (blocks >= 2000).
__global__ void __launch_bounds__(256) k_prep(
    const float* __restrict__ feat, const float* __restrict__ mm,
    const float* __restrict__ q1, const float* __restrict__ q2,
    const int* __restrict__ nn,
    u16* __restrict__ gS, u16* __restrict__ a8, u16* __restrict__ b8,
    int* __restrict__ nnT) {
  const int bid = blockIdx.x;
  if (bid >= 2000) {
    const int i = (bid - 2000)*256 + threadIdx.x;
    if (i < KK1*NNODE) {
      const int k = i / NNODE;
      const int n = i - k*NNODE;
      nnT[i] = nn[n*KK1 + k];
    }
    return;
  }
  const int lane = threadIdx.x & 63;
  const int h = lane >> 4, i = lane & 15;
  const int x = bid & 7;                        // XCD band
  const int mbase = x*10000 + (bid >> 3)*40 + (threadIdx.x >> 6);
  float Mrow[16], Qrow[16];
  const float* qsrc = (i < 8) ? (q1 + (h*8 + i)*16) : (q2 + (h*8 + (i - 8))*16);
#pragma unroll
  for (int j = 0; j < 16; ++j) {
    Mrow[j] = mm[(h*16 + i)*16 + j];
    Qrow[j] = qsrc[j];
  }
#pragma unroll 2
  for (int l = 0; l < 10; ++l) {
    const int m = mbase + l*4;                  // 4 waves cover consecutive m
    const int bt = m / NNODE;
    const int n = m - bt*NNODE;
    const float4* fp = reinterpret_cast<const float4*>(feat + (size_t)m*64 + h*16);
    float fv[16];
#pragma unroll
    for (int q = 0; q < 4; ++q) {
      float4 v = fp[q];
      fv[q*4+0] = v.x; fv[q*4+1] = v.y; fv[q*4+2] = v.z; fv[q*4+3] = v.w;
    }
    float accG = 0.f, accQ = 0.f;
#pragma unroll
    for (int j = 0; j < 16; ++j) {
      accG = fmaf(Mrow[j], fv[j], accG);
      accQ = fmaf(Qrow[j], fv[j], accQ);
    }
    gS[((size_t)(bt*4 + h)*NNODE + n)*16 + i] = f2bf(accG);
    if (i < 8) a8[(size_t)m*32 + h*8 + i] = f2bf(accQ);
    else       b8[(size_t)m*32 + h*8 + (i - 8)] = f2bf(accQ);
  }
}

// ---------------------------------------------------------------------------
// k_w: per (bt,h) slice staged in LDS (160000 B, XOR-swizzled), compute
// w[n][k] bf16 + deg[n] f32 for a 1250-node chunk. All j-gathers from LDS.
// bid = (bt*4+h) + 64*chunk  (chunks of same slice land on same XCD: +64 == 0 mod 8)
__global__ void __launch_bounds__(256) k_w(
    const u16* __restrict__ gS, const int* __restrict__ nnT,
    float* __restrict__ degS, u16* __restrict__ wS) {
  __shared__ u32 glds[40000];                   // 160000 B
  const int bid = blockIdx.x;
  const int sl = bid & 63;                      // bt*4+h
  const int chunk = bid >> 6;                   // 0..3
  // ---- stage: row n = 8 u32, word c at glds[n*8 + (c ^ ((n>>2)&7))]
  const u32* gsrc = reinterpret_cast<const u32*>(gS) + (size_t)sl*NNODE*8;
  for (int n = threadIdx.x; n < NNODE; n += 256) {
    const uint4* rp = reinterpret_cast<const uint4*>(gsrc + n*8);
    uint4 v0 = rp[0], v1 = rp[1];
    u32 wv[8] = {v0.x, v0.y, v0.z, v0.w, v1.x, v1.y, v1.z, v1.w};
    const int sw = (n >> 2) & 7;
#pragma unroll
    for (int c = 0; c < 8; ++c) glds[n*8 + (c ^ sw)] = wv[c];
  }
  __syncthreads();
  // ---- compute
  for (int r = 0; r < 5; ++r) {
    const int ns = r*256 + threadIdx.x;
    if (ns >= 1250) continue;
    const int n = chunk*1250 + ns;
    float av[16];
    float si = 0.f;
    const int swn = (n >> 2) & 7;
#pragma unroll
    for (int c = 0; c < 8; ++c) {
      u32 wv = glds[n*8 + (c ^ swn)];
      float lo = bfLo(wv), hi = bfHi(wv);
      av[2*c] = lo; av[2*c+1] = hi;
      si = fmaf(lo, lo, si); si = fmaf(hi, hi, si);
    }
    float deg = 0.f;
    u32 packed[8];
#pragma unroll 4
    for (int k = 0; k < 16; ++k) {
      const int jr = nnT[(1 + k)*NNODE + n];
      const int j = (jr >= 0) ? jr : 0;
      const int swj = (j >> 2) & 7;
      float dot = 0.f, sj = 0.f;
#pragma unroll
      for (int c = 0; c < 8; ++c) {
        u32 wv = glds[j*8 + (c ^ swj)];
        float lo = bfLo(wv), hi = bfHi(wv);
        dot = fmaf(av[2*c], lo, dot); dot = fmaf(av[2*c+1], hi, dot);
        sj = fmaf(lo, lo, sj); sj = fmaf(hi, hi, sj);
      }
      float e = si + sj - 2.f*dot;
      float w = (jr >= 0) ? __expf(-e) : 0.f;
      deg += w;
      u16 wb = f2bf(w);
      if (k & 1) packed[k >> 1] |= ((u32)wb) << 16;
      else       packed[k >> 1] = (u32)wb;
    }
    degS[(size_t)sl*NNODE + n] = deg;
    uint4* wp = reinterpret_cast<uint4*>(wS + ((size_t)sl*NNODE + n)*16);
    wp[0] = make_uint4(packed[0], packed[1], packed[2], packed[3]);
    wp[1] = make_uint4(packed[4], packed[5], packed[6], packed[7]);
  }
}

// ---------------------------------------------------------------------------
// k_uw3: per bt, stage deg slice [h][n] (80000 B) in LDS; normalize and emit
// u_w in final [bt][n][k][h] layout via 2 contiguous float4/thread.
// bid = bt + 16*chunk (16 chunks of 313 nodes)
__global__ void __launch_bounds__(256) k_uw3(
    const u16* __restrict__ wS, const int* __restrict__ nnT,
    const float* __restrict__ degS, float* __restrict__ uw) {
  __shared__ float dl[4*NNODE];                 // 80000 B, [h][n]
  const int bid = blockIdx.x;
  const int bt = bid & 15;
  const int chunk = bid >> 4;                   // 0..15
  for (int i = threadIdx.x; i < 4*NNODE; i += 256) dl[i] = degS[(size_t)bt*4*NNODE + i];
  __syncthreads();
  const u32* wsrc = reinterpret_cast<const u32*>(wS);
  for (int r = 0; r < 10; ++r) {
    const int item = r*256 + threadIdx.x;       // < 313*8 = 2504
    const int nsub = item >> 3, kp = item & 7;
    const int n = chunk*313 + nsub;
    if (nsub >= 313 || n >= NNODE) continue;
    const int j0r = nnT[(1 + 2*kp)*NNODE + n];
    const int j1r = nnT[(2 + 2*kp)*NNODE + n];
    const int j0 = (j0r >= 0) ? j0r : 0;
    const int j1 = (j1r >= 0) ? j1r : 0;
    u32 wv[4];
#pragma unroll
    for (int h = 0; h < 4; ++h) wv[h] = wsrc[((size_t)(bt*4 + h)*NNODE + n)*8 + kp];
    float o0[4], o1[4];
#pragma unroll
    for (int h = 0; h < 4; ++h) {
      const float di  = dl[h*NNODE + n];
      const float dj0 = dl[h*NNODE + j0];
      const float dj1 = dl[h*NNODE + j1];
      const float w0 = bfLo(wv[h]), w1 = bfHi(wv[h]);
      const float p0 = di*dj0, p1 = di*dj1;
      o0[h] = (j0r >= 0 && w0 > 0.f && p0 > 0.f) ? w0*rsqrtf(p0) : 0.f;
      o1[h] = (j1r >= 0 && w1 > 0.f && p1 > 0.f) ? w1*rsqrtf(p1) : 0.f;
    }
    float4* ob = reinterpret_cast<float4*>(uw + (((size_t)bt*NNODE + n)*16 + 2*kp)*4);
    ob[0] = make_float4(o0[0], o0[1], o0[2], o0[3]);
    ob[1] = make_float4(o1[0], o1[1], o1[2], o1[3]);
  }
}

// ---------------------------------------------------------------------------
// k_dw: unchanged R6 structure. d_w[rest][k*4+h]; nn dedup via quad-shuffle;
// LDS transpose epilogue. Grid 1094 (bijective 8-way).
__global__ void __launch_bounds__(256) k_dw(
    const u16* __restrict__ a8, const u16* __restrict__ b8,
    const int* __restrict__ nn, float* __restrict__ dw) {
  __shared__ float lds[64*68];
  const int bid = blockIdx.x;
  const int x = bid & 7, sub = bid >> 3;
  const int wg = (x < 6 ? x*137 : 6*137 + (x-6)*136) + sub;
  const int lr = threadIdx.x >> 2;
  const int h  = threadIdx.x & 3;
  const int lane = threadIdx.x & 63;
  const int qbase = lane & ~3;
  const int rest = wg*64 + lr;
  if (rest < NREST) {
    const int n = rest % NNODE;
    const int q2 = rest / NNODE;                // 0..13
    const int b = q2 / 7, t = q2 % 7;
    uint4 Bv = *reinterpret_cast<const uint4*>(b8 + ((size_t)((b*8 + t + 1)*NNODE + n))*32 + h*8);
    float bv[8] = {bfLo(Bv.x), bfHi(Bv.x), bfLo(Bv.y), bfHi(Bv.y),
                   bfLo(Bv.z), bfHi(Bv.z), bfLo(Bv.w), bfHi(Bv.w)};
    const int nbase = n*KK1;
    const int abase = (b*8 + t)*NNODE;
    int jvec[4];
    jvec[0] = nn[nbase + h + 0];
    jvec[1] = nn[nbase + h + 4];
    jvec[2] = nn[nbase + h + 8];
    jvec[3] = nn[nbase + h + 12];
    int j16 = nn[nbase + 16];
    float wk[17];
    float indeg = 0.f;
#pragma unroll
    for (int kk = 0; kk < 16; ++kk) {
      int jr = __shfl(jvec[kk >> 2], qbase + (kk & 3));
      bool valid = jr >= 0;
      int j = valid ? jr : 0;
      uint4 Av = *reinterpret_cast<const uint4*>(a8 + ((size_t)(abase + j))*32 + h*8);
      float dot = 0.f;
      dot = fmaf(bfLo(Av.x), bv[0], dot); dot = fmaf(bfHi(Av.x), bv[1], dot);
      dot = fmaf(bfLo(Av.y), bv[2], dot); dot = fmaf(bfHi(Av.y), bv[3], dot);
      dot = fmaf(bfLo(Av.z), bv[4], dot); dot = fmaf(bfHi(Av.z), bv[5], dot);
      dot = fmaf(bfLo(Av.w), bv[6], dot); dot = fmaf(bfHi(Av.w), bv[7], dot);
      float w = valid ? __expf(-dot) : 0.f;
      wk[kk] = w;
      indeg += w;
    }
    {
      bool valid = j16 >= 0;
      int j = valid ? j16 : 0;
      uint4 Av = *reinterpret_cast<const uint4*>(a8 + ((size_t)(abase + j))*32 + h*8);
      float dot = 0.f;
      dot = fmaf(bfLo(Av.x), bv[0], dot); dot = fmaf(bfHi(Av.x), bv[1], dot);
      dot = fmaf(bfLo(Av.y), bv[2], dot); dot = fmaf(bfHi(Av.y), bv[3], dot);
      dot = fmaf(bfLo(Av.z), bv[4], dot); dot = fmaf(bfHi(Av.z), bv[5], dot);
      dot = fmaf(bfLo(Av.w), bv[6], dot); dot = fmaf(bfHi(Av.w), bv[7], dot);
      float w = valid ? __expf(-dot) : 0.f;
      wk[16] = w;
      indeg += w;
    }
    float inv = (indeg > 0.f) ? (1.0f / indeg) : 0.f;
#pragma unroll
    for (int kk = 0; kk < KK1; ++kk) lds[lr*68 + kk*4 + h] = wk[kk] * inv;
  }
  __syncthreads();
  const int rows = NREST - wg*64;
  const int nchunks = (rows >= 64 ? 64 : rows) * 17;
  float4* obase = reinterpret_cast<float4*>(dw + (size_t)wg*4352);
  for (int c = threadIdx.x; c < nchunks; c += 256) {
    const int row = c / 17;
    const int col = (c % 17) * 4;
    obase[c] = *reinterpret_cast<const float4*>(&lds[row*68 + col]);
  }
}

extern "C" void kernel_launch(void* const* d_in, const int* in_sizes, int n_in,
                              void* d_out, int out_size, void* d_ws, size_t ws_size,
                              hipStream_t stream) {
  const float* feat = (const float*)d_in[0];
  const int*   nn   = (const int*)d_in[1];
  const float* q1   = (const float*)d_in[2];
  const float* q2   = (const float*)d_in[3];
  const float* mm   = (const float*)d_in[4];
  float* uw = (float*)d_out;
  float* dw = uw + (size_t)NT*64;

  // FIXED R8 bug: gS is NT*64 u16 (80000 nodes x 4h x 16 dims) = 10,240,000 B,
  // not NT*16*2. The old value made a8/b8 overlap gS -> corrupted outputs.
  const size_t GS_BYTES = (size_t)NT*64*2;      // 10,240,000
  const size_t A_BYTES  = (size_t)NT*32*2;      //  5,120,000 each
  const size_t DEG_BYTES= (size_t)64*NNODE*4;   //  1,280,000 (64 (bt,h)-slices x 5000 f32)
  const size_t W_BYTES  = (size_t)64*NNODE*16*2;// 10,240,000
  const size_t NNT_BYTES= (size_t)KK1*NNODE*4;  //    340,000
  const size_t NEED = GS_BYTES + 2*A_BYTES + DEG_BYTES + W_BYTES + NNT_BYTES;  // 32.34 MB
  if (ws_size < NEED) {
    fprintf(stderr, "kernel_launch: ws_size %zu < needed %zu\n", ws_size, NEED);
    return;
  }
  u16*   gS   = (u16*)d_ws;
  u16*   a8   = (u16*)((char*)d_ws + GS_BYTES);
  u16*   b8   = (u16*)((char*)d_ws + GS_BYTES + A_BYTES);
  float* degS = (float*)((char*)d_ws + GS_BYTES + 2*A_BYTES);
  u16*   wS   = (u16*)((char*)d_ws + GS_BYTES + 2*A_BYTES + DEG_BYTES);
  int*   nnT  = (int*)((char*)d_ws + GS_BYTES + 2*A_BYTES + DEG_BYTES + W_BYTES);

  k_prep<<<2333, 256, 0, stream>>>(feat, mm, q1, q2, nn, gS, a8, b8, nnT);
  k_w   <<<256, 256, 0, stream>>>(gS, nnT, degS, wS);
  k_uw3 <<<256, 256, 0, stream>>>(wS, nnT, degS, uw);
  k_dw  <<<1094, 256, 0, stream>>>(a8, b8, nn, dw);
}